// Round 1
// baseline (420.136 us; speedup 1.0000x reference)
//
#include <hip/hip_runtime.h>
#include <math.h>

constexpr int N   = 4096;   // nodes
constexpr int F   = 256;    // IN_FEAT (= NH*HID)
constexpr int NH  = 8;      // heads
constexpr int HID = 32;     // hidden per head
constexpr float SLOPE = 0.2f;

// ---------------- K1: g = h @ W^T  (fp32) ----------------
// grid 256 blocks (16 rows each), 256 threads; h-tile in LDS (broadcast reads),
// each thread owns one output column and streams its W row through L1.
__global__ __launch_bounds__(256) void k_gemm(const float* __restrict__ h,
                                              const float* __restrict__ W,
                                              float* __restrict__ g) {
  __shared__ float hs[16][F];
  const int t  = threadIdx.x;
  const int i0 = blockIdx.x * 16;
  {
    const int r = t >> 4, c0 = (t & 15) * 16;
    const float4* src = (const float4*)(h + (size_t)(i0 + r) * F + c0);
    float4* dst = (float4*)&hs[r][c0];
#pragma unroll
    for (int q = 0; q < 4; ++q) dst[q] = src[q];
  }
  __syncthreads();
  float acc[16];
#pragma unroll
  for (int i = 0; i < 16; ++i) acc[i] = 0.f;
  const float4* Wrow = (const float4*)(W + (size_t)t * F);
  for (int kq = 0; kq < F / 4; ++kq) {
    const float4 wv = Wrow[kq];
#pragma unroll
    for (int i = 0; i < 16; ++i) {
      const float4 hv = *(const float4*)&hs[i][kq * 4];
      acc[i] += hv.x * wv.x + hv.y * wv.y + hv.z * wv.z + hv.w * wv.w;
    }
  }
#pragma unroll
  for (int i = 0; i < 16; ++i) g[(size_t)(i0 + i) * F + t] = acc[i];
}

// ---------------- K2: s_i, s_j ----------------
__global__ __launch_bounds__(256) void k_sisj(const float* __restrict__ g,
                                              const float* __restrict__ a,
                                              float* __restrict__ si,
                                              float* __restrict__ sj) {
  const int idx = blockIdx.x * 256 + threadIdx.x;  // n*8 + h
  const int n = idx >> 3, hh = idx & 7;
  const float4* gp = (const float4*)(g + (size_t)n * F + hh * HID);
  const float4* al = (const float4*)a;
  const float4* ar = (const float4*)(a + HID);
  float sl = 0.f, sr = 0.f;
#pragma unroll
  for (int q = 0; q < HID / 4; ++q) {
    const float4 gv = gp[q];
    const float4 av = al[q], bv = ar[q];
    sl += gv.x * av.x + gv.y * av.y + gv.z * av.z + gv.w * av.w;
    sr += gv.x * bv.x + gv.y * bv.y + gv.z * bv.z + gv.w * bv.w;
  }
  si[idx] = sl;
  sj[idx] = sr;
}

// ---------------- K3: masked max over s_j + bitmask pack ----------------
// m[i][h] = lrelu(si[i][h] + max_{j: adj!=0} sj[j][h])  (lrelu is monotone)
__global__ __launch_bounds__(256) void k_maxbits(const int* __restrict__ adj,
                                                 const float* __restrict__ si,
                                                 const float* __restrict__ sj,
                                                 float* __restrict__ m,
                                                 unsigned int* __restrict__ bits) {
  __shared__ float red[4][8];
  const int i = blockIdx.x;
  const int t = threadIdx.x;
  float pm[8];
#pragma unroll
  for (int hh = 0; hh < 8; ++hh) pm[hh] = -INFINITY;
  const int* arow = adj + (size_t)i * N;
  for (int c = 0; c < N / 256; ++c) {
    const int j = c * 256 + t;
    const bool bit = arow[j] != 0;
    const unsigned long long bal = __ballot(bit);
    if ((t & 63) == 0) {
      *(unsigned long long*)(bits + (size_t)i * (N / 32) + (j >> 5)) = bal;
    }
    const float4 s0 = *(const float4*)(sj + (size_t)j * 8);
    const float4 s1 = *(const float4*)(sj + (size_t)j * 8 + 4);
    if (bit) {
      pm[0] = fmaxf(pm[0], s0.x); pm[1] = fmaxf(pm[1], s0.y);
      pm[2] = fmaxf(pm[2], s0.z); pm[3] = fmaxf(pm[3], s0.w);
      pm[4] = fmaxf(pm[4], s1.x); pm[5] = fmaxf(pm[5], s1.y);
      pm[6] = fmaxf(pm[6], s1.z); pm[7] = fmaxf(pm[7], s1.w);
    }
  }
#pragma unroll
  for (int hh = 0; hh < 8; ++hh) {
#pragma unroll
    for (int o = 32; o > 0; o >>= 1) pm[hh] = fmaxf(pm[hh], __shfl_xor(pm[hh], o));
  }
  if ((t & 63) == 0) {
    const int wv = t >> 6;
#pragma unroll
    for (int hh = 0; hh < 8; ++hh) red[wv][hh] = pm[hh];
  }
  __syncthreads();
  if (t < 8) {
    const float mx = fmaxf(fmaxf(red[0][t], red[1][t]), fmaxf(red[2][t], red[3][t]));
    const float x = si[(size_t)i * 8 + t] + mx;
    m[(size_t)i * 8 + t] = x > 0.f ? x : SLOPE * x;
  }
}

// ---------------- K4: softmax weights + aggregation ----------------
// block = (i-tile of 16) x (head pair); grid = 256*4 = 1024 blocks.
// chunked over j (JC=64): phase A computes w into LDS, phase B accumulates.
constexpr int TI   = 16;
constexpr int JC   = 64;
constexpr int GS   = 68;  // LDS g row stride (floats): 272B = 17*16B, keeps float4 align
constexpr int WSTR = 33;  // LDS w row stride (floats): odd -> conflict-free

__global__ __launch_bounds__(256, 4) void k_agg(const float* __restrict__ g,
                                                const float* __restrict__ si,
                                                const float* __restrict__ sj,
                                                const float* __restrict__ m,
                                                const unsigned int* __restrict__ bits,
                                                float* __restrict__ out) {
  __shared__ float sG[JC][GS];     // g chunk: 64 j x 64 feats (head pair)
  __shared__ float sW[JC][WSTR];   // w: 64 j x (16 i * 2 h)
  __shared__ float sL[TI * 2];
  const int t  = threadIdx.x;
  const int hp = blockIdx.x & 3;          // head pair 0..3 -> heads hp*2, hp*2+1
  const int i0 = (blockIdx.x >> 2) * TI;

  // phase-A persona: (jA = j within chunk, grp -> 4 i-rows)
  const int jA  = t & 63;
  const int grp = t >> 6;
  float siR[4][2], mR[4][2];
#pragma unroll
  for (int ii = 0; ii < 4; ++ii) {
    const int gi = i0 + grp * 4 + ii;
#pragma unroll
    for (int hh = 0; hh < 2; ++hh) {
      siR[ii][hh] = si[(size_t)gi * 8 + hp * 2 + hh];
      mR[ii][hh]  = m[(size_t)gi * 8 + hp * 2 + hh];
    }
  }

  // staging persona: 4 consecutive lanes cover 64B of one g row
  const int gRow = t >> 2;
  const int gq   = t & 3;

  // phase-B persona: (i, h, feature-quad)
  const int iB = t >> 4;
  const int hB = (t >> 3) & 1;
  const int fq = t & 7;
  float4 acc = make_float4(0.f, 0.f, 0.f, 0.f);
  float lacc = 0.f;

  for (int c = 0; c < N / JC; ++c) {
    const int j0 = c * JC;
    __syncthreads();
    // stage g chunk (coalesced: lanes 0..3 read contiguous 64B)
    {
      const float4* src = (const float4*)(g + (size_t)(j0 + gRow) * F + hp * 64);
#pragma unroll
      for (int r = 0; r < 4; ++r) {
        *(float4*)&sG[gRow][(gq + r * 4) * 4] = src[gq + r * 4];
      }
    }
    // compute w = adj ? exp(lrelu(si+sj) - m) : 0
    {
      const float2 sjv = *(const float2*)(sj + (size_t)(j0 + jA) * 8 + hp * 2);
      const float sjh[2] = {sjv.x, sjv.y};
#pragma unroll
      for (int ii = 0; ii < 4; ++ii) {
        const int il = grp * 4 + ii;
        const unsigned int word = bits[(size_t)(i0 + il) * (N / 32) + ((j0 + jA) >> 5)];
        const bool bit = (word >> (jA & 31)) & 1u;
#pragma unroll
        for (int hh = 0; hh < 2; ++hh) {
          const float x = siR[ii][hh] + sjh[hh];
          const float e = x > 0.f ? x : SLOPE * x;
          const float w = bit ? __expf(e - mR[ii][hh]) : 0.f;
          sW[jA][il * 2 + hh] = w;
        }
      }
    }
    __syncthreads();
    // aggregate: acc[f] += w * g[j][f], l += w
    {
      const float* wp = &sW[0][iB * 2 + hB];
      const float* gp = &sG[0][hB * 32 + fq * 4];
#pragma unroll
      for (int j = 0; j < JC; ++j) {
        const float w = wp[(size_t)j * WSTR];
        const float4 gv = *(const float4*)(gp + (size_t)j * GS);
        acc.x += w * gv.x; acc.y += w * gv.y;
        acc.z += w * gv.z; acc.w += w * gv.w;
        lacc += w;
      }
    }
  }
  if (fq == 0) sL[iB * 2 + hB] = lacc;
  __syncthreads();
  const float inv = 1.f / sL[iB * 2 + hB];
  float4 res;
  res.x = acc.x * inv; res.y = acc.y * inv;
  res.z = acc.z * inv; res.w = acc.w * inv;
  *(float4*)(out + (size_t)(i0 + iB) * F + (hp * 2 + hB) * HID + fq * 4) = res;
}

extern "C" void kernel_launch(void* const* d_in, const int* in_sizes, int n_in,
                              void* d_out, int out_size, void* d_ws, size_t ws_size,
                              hipStream_t stream) {
  const float* h   = (const float*)d_in[0];
  const float* W   = (const float*)d_in[1];
  const float* a   = (const float*)d_in[2];
  const int*   adj = (const int*)d_in[3];
  float* out = (float*)d_out;

  // workspace layout (total ~6.4 MB)
  float* wsf = (float*)d_ws;
  float* g  = wsf;                         // 4096*256
  float* si = g  + (size_t)N * F;          // 4096*8
  float* sj = si + (size_t)N * NH;         // 4096*8
  float* m  = sj + (size_t)N * NH;         // 4096*8
  unsigned int* bits = (unsigned int*)(m + (size_t)N * NH);  // 4096*128 words

  k_gemm<<<dim3(N / 16), dim3(256), 0, stream>>>(h, W, g);
  k_sisj<<<dim3(N * NH / 256), dim3(256), 0, stream>>>(g, a, si, sj);
  k_maxbits<<<dim3(N), dim3(256), 0, stream>>>(adj, si, sj, m, bits);
  k_agg<<<dim3((N / TI) * 4), dim3(256), 0, stream>>>(g, si, sj, m, bits, out);
}

// Round 2
// 229.580 us; speedup vs baseline: 1.8300x; 1.8300x over previous
//
#include <hip/hip_runtime.h>
#include <math.h>

constexpr int N   = 4096;   // nodes
constexpr int F   = 256;    // IN_FEAT (= NH*HID)
constexpr int NH  = 8;      // heads
constexpr int HID = 32;     // hidden per head
constexpr float SLOPE = 0.2f;

using frag_ab = __attribute__((ext_vector_type(8))) short;  // 8 bf16
using frag_cd = __attribute__((ext_vector_type(4))) float;  // 4 fp32

__device__ inline short f2bf(float x) {  // RNE fp32->bf16
  unsigned int u = __float_as_uint(x);
  unsigned int r = (u + 0x7fffu + ((u >> 16) & 1u)) >> 16;
  return (short)r;
}

// ---------------- K1: g = h @ W^T (fp32) + gT (bf16, transposed) ----------------
// 256 blocks x 256 thr; h-tile in LDS; thread owns output col t, 16 rows.
// Epilogue also writes gT[col][i0..i0+15] bf16 (contiguous 32B per thread).
__global__ __launch_bounds__(256) void k_gemm(const float* __restrict__ h,
                                              const float* __restrict__ W,
                                              float* __restrict__ g,
                                              unsigned short* __restrict__ gT) {
  __shared__ float hs[16][F];
  const int t  = threadIdx.x;
  const int i0 = blockIdx.x * 16;
  {
    const int r = t >> 4, c0 = (t & 15) * 16;
    const float4* src = (const float4*)(h + (size_t)(i0 + r) * F + c0);
    float4* dst = (float4*)&hs[r][c0];
#pragma unroll
    for (int q = 0; q < 4; ++q) dst[q] = src[q];
  }
  __syncthreads();
  float acc[16];
#pragma unroll
  for (int i = 0; i < 16; ++i) acc[i] = 0.f;
  const float4* Wrow = (const float4*)(W + (size_t)t * F);
  for (int kq = 0; kq < F / 4; ++kq) {
    const float4 wv = Wrow[kq];
#pragma unroll
    for (int i = 0; i < 16; ++i) {
      const float4 hv = *(const float4*)&hs[i][kq * 4];
      acc[i] += hv.x * wv.x + hv.y * wv.y + hv.z * wv.z + hv.w * wv.w;
    }
  }
#pragma unroll
  for (int i = 0; i < 16; ++i) g[(size_t)(i0 + i) * F + t] = acc[i];
  unsigned short tmp[16];
#pragma unroll
  for (int i = 0; i < 16; ++i) tmp[i] = (unsigned short)f2bf(acc[i]);
  *(int4*)(gT + (size_t)t * N + i0) = *(int4*)tmp;
  *(int4*)(gT + (size_t)t * N + i0 + 8) = *(int4*)(tmp + 8);
}

// ---------------- K2: s_i, s_j ----------------
__global__ __launch_bounds__(256) void k_sisj(const float* __restrict__ g,
                                              const float* __restrict__ a,
                                              float* __restrict__ si,
                                              float* __restrict__ sj) {
  const int idx = blockIdx.x * 256 + threadIdx.x;  // n*8 + h
  const int n = idx >> 3, hh = idx & 7;
  const float4* gp = (const float4*)(g + (size_t)n * F + hh * HID);
  const float4* al = (const float4*)a;
  const float4* ar = (const float4*)(a + HID);
  float sl = 0.f, sr = 0.f;
#pragma unroll
  for (int q = 0; q < HID / 4; ++q) {
    const float4 gv = gp[q];
    const float4 av = al[q], bv = ar[q];
    sl += gv.x * av.x + gv.y * av.y + gv.z * av.z + gv.w * av.w;
    sr += gv.x * bv.x + gv.y * bv.y + gv.z * bv.z + gv.w * bv.w;
  }
  si[idx] = sl;
  sj[idx] = sr;
}

// ---------------- K3: masked max over s_j + bitmask pack ----------------
__global__ __launch_bounds__(256) void k_maxbits(const int* __restrict__ adj,
                                                 const float* __restrict__ si,
                                                 const float* __restrict__ sj,
                                                 float* __restrict__ m,
                                                 unsigned int* __restrict__ bits) {
  __shared__ float red[4][8];
  const int i = blockIdx.x;
  const int t = threadIdx.x;
  float pm[8];
#pragma unroll
  for (int hh = 0; hh < 8; ++hh) pm[hh] = -INFINITY;
  const int* arow = adj + (size_t)i * N;
  for (int c = 0; c < N / 256; ++c) {
    const int j = c * 256 + t;
    const bool bit = arow[j] != 0;
    const unsigned long long bal = __ballot(bit);
    if ((t & 63) == 0) {
      *(unsigned long long*)(bits + (size_t)i * (N / 32) + (j >> 5)) = bal;
    }
    const float4 s0 = *(const float4*)(sj + (size_t)j * 8);
    const float4 s1 = *(const float4*)(sj + (size_t)j * 8 + 4);
    if (bit) {
      pm[0] = fmaxf(pm[0], s0.x); pm[1] = fmaxf(pm[1], s0.y);
      pm[2] = fmaxf(pm[2], s0.z); pm[3] = fmaxf(pm[3], s0.w);
      pm[4] = fmaxf(pm[4], s1.x); pm[5] = fmaxf(pm[5], s1.y);
      pm[6] = fmaxf(pm[6], s1.z); pm[7] = fmaxf(pm[7], s1.w);
    }
  }
#pragma unroll
  for (int hh = 0; hh < 8; ++hh) {
#pragma unroll
    for (int o = 32; o > 0; o >>= 1) pm[hh] = fmaxf(pm[hh], __shfl_xor(pm[hh], o));
  }
  if ((t & 63) == 0) {
    const int wv = t >> 6;
#pragma unroll
    for (int hh = 0; hh < 8; ++hh) red[wv][hh] = pm[hh];
  }
  __syncthreads();
  if (t < 8) {
    const float mx = fmaxf(fmaxf(red[0][t], red[1][t]), fmaxf(red[2][t], red[3][t]));
    const float x = si[(size_t)i * 8 + t] + mx;
    m[(size_t)i * 8 + t] = x > 0.f ? x : SLOPE * x;
  }
}

// ---------------- K4: MFMA flash-style aggregation ----------------
// block = 32 i-rows x head-pair; 4 waves: wave w -> (isub = w&1, hh = w>>1).
// Per k-step (32 j): w computed by VALU directly into A-frag regs;
// B-frag = ds_read_b128 from bf16 gT chunk; l via per-lane sum + shuffle.
constexpr int TI = 32;
constexpr int JC = 128;

__global__ __launch_bounds__(256, 2) void k_agg(
    const unsigned short* __restrict__ gT,
    const float* __restrict__ si, const float* __restrict__ sj,
    const float* __restrict__ m, const unsigned int* __restrict__ bits,
    float* __restrict__ out) {
  __shared__ __align__(16) unsigned short sB[64][136];  // gT chunk: row=hh*32+f, col=j
  __shared__ float sSj[2][JC];
  __shared__ unsigned int sBits[TI][JC / 32];
  __shared__ float sLl[4][16];

  const int t    = threadIdx.x;
  const int lane = t & 63;
  const int wv   = t >> 6;
  const int isub = wv & 1;
  const int hh   = wv >> 1;
  const int hp   = blockIdx.x & 3;
  const int i0   = (blockIdx.x >> 2) * TI;
  const int head = hp * 2 + hh;

  const int n16  = lane & 15;
  const int quad = lane >> 4;

  const int myi   = i0 + isub * 16 + n16;
  const float siv = si[(size_t)myi * 8 + head];
  const float mv  = m[(size_t)myi * 8 + head];

  frag_cd acc0 = {0.f, 0.f, 0.f, 0.f};
  frag_cd acc1 = {0.f, 0.f, 0.f, 0.f};
  float lpart = 0.f;

  // staging persona for gT: row r = t>>2, segment start s0 = t&3
  const int sr = t >> 2, ss0 = t & 3;

  for (int c = 0; c < N / JC; ++c) {
    const int j0 = c * JC;
    __syncthreads();
    {  // stage gT rows (64 x 128 bf16), coalesced 64B per 4 lanes
      const unsigned short* src = gT + (size_t)(hp * 64 + sr) * N + j0;
#pragma unroll
      for (int s = 0; s < 4; ++s) {
        const int seg = ss0 + s * 4;
        *(int4*)&sB[sr][seg * 8] = *(const int4*)(src + seg * 8);
      }
    }
    {  // stage sj chunk, transposed per head
      const int jj = t >> 1, hs = t & 1;
      sSj[hs][jj] = sj[(size_t)(j0 + jj) * 8 + hp * 2 + hs];
    }
    if (t < TI * (JC / 32)) {  // stage bits chunk
      const int ir = t >> 2, wd = t & 3;
      sBits[ir][wd] = bits[(size_t)(i0 + ir) * (N / 32) + (j0 >> 5) + wd];
    }
    __syncthreads();
#pragma unroll
    for (int ks = 0; ks < JC / 32; ++ks) {
      const int jb = ks * 32 + quad * 8;  // lane's j-offset within chunk
      const unsigned int word = sBits[isub * 16 + n16][ks];
      const float* sjp = &sSj[hh][jb];
      frag_ab af;
#pragma unroll
      for (int u = 0; u < 8; ++u) {
        const float x = siv + sjp[u];
        const float e = fmaxf(x, SLOPE * x);
        const float ww = ((word >> (quad * 8 + u)) & 1u) ? __expf(e - mv) : 0.f;
        lpart += ww;
        af[u] = f2bf(ww);
      }
      const frag_ab b0 = *(const frag_ab*)&sB[hh * 32 + n16][jb];
      const frag_ab b1 = *(const frag_ab*)&sB[hh * 32 + 16 + n16][jb];
      acc0 = __builtin_amdgcn_mfma_f32_16x16x32_bf16(af, b0, acc0, 0, 0, 0);
      acc1 = __builtin_amdgcn_mfma_f32_16x16x32_bf16(af, b1, acc1, 0, 0, 0);
    }
  }
  // full l per i: butterfly over the 4 quads
  lpart += __shfl_xor(lpart, 16);
  lpart += __shfl_xor(lpart, 32);
  if (quad == 0) sLl[wv][n16] = lpart;
  __syncthreads();
  // epilogue: C layout col=n16, row=quad*4+reg
#pragma unroll
  for (int reg = 0; reg < 4; ++reg) {
    const int row = quad * 4 + reg;
    const float inv = 1.f / sLl[wv][row];
    const int gi = i0 + isub * 16 + row;
    out[(size_t)gi * F + head * HID + n16]      = acc0[reg] * inv;
    out[(size_t)gi * F + head * HID + 16 + n16] = acc1[reg] * inv;
  }
}

extern "C" void kernel_launch(void* const* d_in, const int* in_sizes, int n_in,
                              void* d_out, int out_size, void* d_ws, size_t ws_size,
                              hipStream_t stream) {
  const float* h   = (const float*)d_in[0];
  const float* W   = (const float*)d_in[1];
  const float* a   = (const float*)d_in[2];
  const int*   adj = (const int*)d_in[3];
  float* out = (float*)d_out;

  // workspace: g (4MB) | si,sj,m (96KB) | bits (2MB) | gT (2MB)
  float* wsf = (float*)d_ws;
  float* g  = wsf;
  float* si = g  + (size_t)N * F;
  float* sj = si + (size_t)N * NH;
  float* m  = sj + (size_t)N * NH;
  unsigned int* bits = (unsigned int*)(m + (size_t)N * NH);
  unsigned short* gT = (unsigned short*)(bits + (size_t)N * (N / 32));

  k_gemm<<<dim3(N / 16), dim3(256), 0, stream>>>(h, W, g, gT);
  k_sisj<<<dim3(N * NH / 256), dim3(256), 0, stream>>>(g, a, si, sj);
  k_maxbits<<<dim3(N), dim3(256), 0, stream>>>(adj, si, sj, m, bits);
  k_agg<<<dim3((N / TI) * 4), dim3(256), 0, stream>>>(gT, si, sj, m, bits, out);
}